// Round 21
// baseline (2085.362 us; speedup 1.0000x reference)
//
#include <hip/hip_runtime.h>
#include <math.h>

#define BATCH 4096
#define NIN   4096
#define NOUT  4096
// R9-verified ACID ORDER (frozen): [512x8] k-panels, single ascending fmaf
// chain, fold every 512 k, f32 epilogue. BASE on MFMA pipe (R13/R19-verified).
// R21: acid B-signs stored bf16 PERMUTED (signP[k][g*128+tx*8+j]) so each
// thread's 8 signs = one b128; DS/wave-k 4->3 b128 (-25%), unpack = 8 shifts
// (+12% VALU, affordable: DS was binder at 74% VALUBusy). R17 retry in the
// correct regime. Tail fusion + merged precompute kept from R20.

typedef __attribute__((ext_vector_type(8))) short bf16x8;
typedef __attribute__((ext_vector_type(8))) unsigned short u16x8;
typedef __attribute__((ext_vector_type(4))) float f32x4;

__device__ __forceinline__ float2 compute_terms(float xv) {
    float h  = (float)exp10(-(double)xv);
    float oh = 1e-14f / h;
    return make_float2(h * 0.1f, oh * 0.1f);
}
__device__ __forceinline__ unsigned short bf16_rne(float v) {
    unsigned int b = __float_as_uint(v);
    return (unsigned short)((b + 0x7FFFu + ((b >> 16) & 1u)) >> 16);
}
__device__ __forceinline__ float signf_of(float wv) {
    return (wv > 0.f) ? 1.f : ((wv < 0.f) ? -1.f : 0.f);
}
__device__ __forceinline__ unsigned short signbf16_of(float wv) {
    return (wv > 0.f) ? 0x3F80u : ((wv < 0.f) ? 0xBF80u : 0u);
}

#define GLOAD16(g, l)                                                        \
    __builtin_amdgcn_global_load_lds(                                        \
        (const __attribute__((address_space(1))) void*)(g),                  \
        (__attribute__((address_space(3))) void*)(l), 16, 0, 0)

// --- merged precompute ---
// blocks y<64: x -> AaT[k][m] f32 + Ab[m][k] bf16
// blocks y>=64: w -> signT[n][k] bf16 (MFMA B) + signP[k][perm(n)] bf16 (acid B)
// perm within each 128-col group: col (tx*4+j | 64+tx*4+j-4) -> tx*8+j  (bijective)
__global__ __launch_bounds__(256) void precompute_all(const float* __restrict__ x,
                                                      const float* __restrict__ w,
                                                      float* __restrict__ aaT,
                                                      unsigned short* __restrict__ ab,
                                                      unsigned short* __restrict__ sT,
                                                      unsigned short* __restrict__ sP) {
    const int tid = threadIdx.x;
    if (blockIdx.y < 64) {
        __shared__ float tile[64][65];
        const int m0 = blockIdx.y * 64, k0 = blockIdx.x * 64;
        #pragma unroll
        for (int it = 0; it < 4; ++it) {
            int idx = tid + it * 256;
            int row = idx >> 4, q = idx & 15;
            float4 xv = *(const float4*)(x + (size_t)(m0 + row) * NIN + k0 + q * 4);
            float2 t0 = compute_terms(xv.x), t1 = compute_terms(xv.y),
                   t2 = compute_terms(xv.z), t3 = compute_terms(xv.w);
            *(ushort4*)(ab + (size_t)(m0 + row) * NIN + k0 + q * 4) =
                make_ushort4(bf16_rne(t0.y), bf16_rne(t1.y), bf16_rne(t2.y), bf16_rne(t3.y));
            tile[row][q * 4 + 0] = t0.x; tile[row][q * 4 + 1] = t1.x;
            tile[row][q * 4 + 2] = t2.x; tile[row][q * 4 + 3] = t3.x;
        }
        __syncthreads();
        #pragma unroll
        for (int it = 0; it < 4; ++it) {
            int idx = tid + it * 256;
            int krow = idx >> 4, q = idx & 15;
            float4 v = make_float4(tile[q * 4 + 0][krow], tile[q * 4 + 1][krow],
                                   tile[q * 4 + 2][krow], tile[q * 4 + 3][krow]);
            *(float4*)(aaT + (size_t)(k0 + krow) * NIN + m0 + q * 4) = v;
        }
    } else {
        __shared__ unsigned short tileu[64][68];
        const int k0 = (blockIdx.y - 64) * 64, n0 = blockIdx.x * 64;
        #pragma unroll
        for (int it = 0; it < 4; ++it) {
            int idx = tid + it * 256;
            int krow = idx >> 4, q = idx & 15;
            float4 wv = *(const float4*)(w + (size_t)(k0 + krow) * NOUT + n0 + q * 4);
            ushort4 sg = make_ushort4(signbf16_of(wv.x), signbf16_of(wv.y),
                                      signbf16_of(wv.z), signbf16_of(wv.w));
            *(ushort4*)&tileu[krow][q * 4] = sg;
            // permuted acid-sign write: 4 consecutive cols stay consecutive
            int c0  = n0 + q * 4;
            int grp = c0 >> 7, wi = c0 & 127;
            int pos = grp * 128 + ((wi & 63) >> 2) * 8 + ((wi >> 6) & 1) * 4;
            *(ushort4*)(sP + (size_t)(k0 + krow) * NOUT + pos) = sg;
        }
        __syncthreads();
        #pragma unroll
        for (int it = 0; it < 2; ++it) {
            int idx = tid + it * 256;
            int n = idx >> 3, kc = idx & 7;
            u16x8 v;
            #pragma unroll
            for (int j = 0; j < 8; ++j) v[j] = tileu[kc * 8 + j][n];
            *(u16x8*)(sT + (size_t)(n0 + n) * NIN + k0 + kc * 8) = v;
        }
    }
}

// --- fused kernel: acid VALU main loop + base MFMA tail (R20 structure) ---
// LDS: As[2][16][128] f32 (16 KB) + BsU[2][16][128] u16 (8 KB) = 24576 B,
// aliased by BoutH[128][68] f32 = 34816 B in the tail -> block LDS 34816.
__global__ __launch_bounds__(256, 3) void acid_base_fused(const float* __restrict__ AaT,
                                                          const unsigned short* __restrict__ SignP,
                                                          const unsigned short* __restrict__ Ab,
                                                          const unsigned short* __restrict__ SignT,
                                                          float* __restrict__ out) {
    __shared__ __align__(16) char smem[34816];
    float (*As)[16][128]          = (float (*)[16][128])smem;                      // [2][16][128] f32
    unsigned short (*BsU)[16][128] = (unsigned short (*)[16][128])(smem + 16384);  // [2][16][128] u16
    float (*BoutH)[68]            = (float (*)[68])smem;                           // tail alias

    const int tid = threadIdx.x;
    const int tx  = tid & 15;      // cols tx*4..+3 and 64+tx*4..+3
    const int ty  = tid >> 4;      // rows ty*8..+7
    const int w   = tid >> 6;      // wave
    const int l   = tid & 63;
    const int g   = l >> 4;        // MFMA k-group
    const int r16 = l & 15;
    const int bm0 = blockIdx.y * 128;
    const int bn0 = blockIdx.x * 128;

    const int lrow = (l >> 5);       // A glds: sub-row within 1024B
    const int lcol = (l & 31) * 4;   // A glds: f32 col
    const int brow = l >> 4;         // B glds: sub-row (256B rows, 4 per 1024B)
    const int bcol = (l & 15) * 8;   // B glds: u16 col

    float ma[8][8] = {}, ca[8][8] = {};

    #define AISSUE(s, b)                                                            \
        {                                                                           \
            const int k0_ = (s) * 16;                                               \
            _Pragma("unroll")                                                       \
            for (int j = 0; j < 2; ++j) {                                           \
                const int kr_ = w * 4 + 2 * j;                                      \
                GLOAD16(AaT + (size_t)(k0_ + kr_ + lrow) * NIN + bm0 + lcol,        \
                        &As[b][kr_][0]);                                            \
            }                                                                       \
            GLOAD16(SignP + (size_t)(k0_ + w * 4 + brow) * NOUT + bn0 + bcol,       \
                    &BsU[b][w * 4][0]);                                             \
        }

    // 16 ascending k; fold every 32 stages (= 512 k, R9-frozen schedule)
    // signs unpacked bit-exactly: lo -> u<<16, hi -> u & 0xFFFF0000
    #define ACOMP(s, b)                                                             \
        {                                                                           \
            _Pragma("unroll 4")                                                     \
            for (int k = 0; k < 16; ++k) {                                          \
                const float4 pa = *(const float4*)&As[b][k][ty * 8];                \
                const float4 pb = *(const float4*)&As[b][k][ty * 8 + 4];            \
                const uint4  su = *(const uint4*)&BsU[b][k][tx * 8];                \
                const float av[8] = {pa.x, pa.y, pa.z, pa.w, pb.x, pb.y, pb.z, pb.w};\
                const float sn[8] = {                                               \
                    __uint_as_float(su.x << 16), __uint_as_float(su.x & 0xFFFF0000u),\
                    __uint_as_float(su.y << 16), __uint_as_float(su.y & 0xFFFF0000u),\
                    __uint_as_float(su.z << 16), __uint_as_float(su.z & 0xFFFF0000u),\
                    __uint_as_float(su.w << 16), __uint_as_float(su.w & 0xFFFF0000u)};\
                _Pragma("unroll")                                                   \
                for (int m = 0; m < 8; ++m)                                         \
                    _Pragma("unroll")                                               \
                    for (int n = 0; n < 8; ++n)                                     \
                        ca[m][n] = fmaf(av[m], sn[n], ca[m][n]);                    \
            }                                                                       \
            if ((((s) + 1) & 31) == 0) {                                            \
                _Pragma("unroll")                                                   \
                for (int m = 0; m < 8; ++m)                                         \
                    _Pragma("unroll")                                               \
                    for (int n = 0; n < 8; ++n) {                                   \
                        ma[m][n] += ca[m][n]; ca[m][n] = 0.f;                       \
                    }                                                               \
            }                                                                       \
        }

    AISSUE(0, 0);
    __syncthreads();   // buf0 ready

    for (int s2 = 0; s2 < 128; ++s2) {
        const int s = 2 * s2;
        AISSUE(s + 1, 1);
        ACOMP(s, 0);
        __syncthreads();
        if (s + 2 < 256) AISSUE(s + 2, 0);
        ACOMP(s + 1, 1);
        __syncthreads();
    }

    // ---- base MFMA tail (R19/R20-verified): acc reuses ca's dead budget ----
    f32x4 acc[2][8] = {};
    {
        const unsigned short* a0 = Ab + (size_t)(bm0 + w * 32 + r16) * NIN + g * 8;
        const unsigned short* a1 = Ab + (size_t)(bm0 + w * 32 + 16 + r16) * NIN + g * 8;
        #pragma unroll 4
        for (int s = 0; s < 128; ++s) {
            const int k0 = s * 32;
            bf16x8 af0 = *(const bf16x8*)(a0 + k0);
            bf16x8 af1 = *(const bf16x8*)(a1 + k0);
            #pragma unroll
            for (int tc = 0; tc < 8; ++tc) {
                bf16x8 bf = *(const bf16x8*)(SignT + (size_t)(bn0 + tc * 16 + r16) * NIN + k0 + g * 8);
                acc[0][tc] = __builtin_amdgcn_mfma_f32_16x16x32_bf16(af0, bf, acc[0][tc], 0, 0, 0);
                acc[1][tc] = __builtin_amdgcn_mfma_f32_16x16x32_bf16(af1, bf, acc[1][tc], 0, 0, 0);
            }
        }
    }

    // ---- combine + epilogue, two column halves (R18/R20-verified) ----
    __syncthreads();   // As/BsU dead; BoutH alias safe
    #pragma unroll
    for (int hh = 0; hh < 2; ++hh) {
        #pragma unroll
        for (int tr = 0; tr < 2; ++tr)
            #pragma unroll
            for (int tc = 0; tc < 4; ++tc)
                #pragma unroll
                for (int rr = 0; rr < 4; ++rr)
                    BoutH[w * 32 + tr * 16 + g * 4 + rr][tc * 16 + r16] = acc[tr][hh * 4 + tc][rr];
        __syncthreads();
        #pragma unroll
        for (int m = 0; m < 8; ++m) {
            const int row = ty * 8 + m;
            const float4 bv = *(const float4*)&BoutH[row][tx * 4];
            const float bb[4] = {bv.x, bv.y, bv.z, bv.w};
            float ph[4];
            #pragma unroll
            for (int n = 0; n < 4; ++n) {
                float r    = ma[m][hh * 4 + n] - bb[n];
                float conc = fabsf(r) / 409.6f;
                float hc   = (r < 0.f) ? (1e-14f / conc) : conc;
                ph[n]      = (-logf(hc)) / 2.302585092994046f;
            }
            *(float4*)(out + (size_t)(bm0 + row) * NOUT + bn0 + hh * 64 + tx * 4) =
                make_float4(ph[0], ph[1], ph[2], ph[3]);
        }
        __syncthreads();
    }
    #undef AISSUE
    #undef ACOMP
}

// Fallback (ws too small): R9's proven all-VALU kernel, on-the-fly terms.
__global__ __launch_bounds__(256, 2) void acid_gemm_fly(const float* __restrict__ X,
                                                        const float* __restrict__ W,
                                                        float* __restrict__ out) {
    __shared__ float2 Asf[32][128 + 2];
    __shared__ float  Bsf[32][64];
    const int tid = threadIdx.x;
    const int tx = tid & 15, ty = tid >> 4;
    const int bm0 = blockIdx.y * 128, bn0 = blockIdx.x * 64;
    float ma[8][4] = {}, mb[8][4] = {}, ca[8][4] = {}, cb[8][4] = {};
    for (int s = 0; s < 128; ++s) {
        const int k0 = s * 32;
        for (int idx = tid; idx < 128 * 32; idx += 256) {
            int m = idx >> 5, k = idx & 31;
            Asf[k][m] = compute_terms(X[(size_t)(bm0 + m) * NIN + k0 + k]);
        }
        for (int idx = tid; idx < 32 * 64; idx += 256) {
            int k = idx >> 6, c = idx & 63;
            Bsf[k][c] = signf_of(W[(size_t)(k0 + k) * NOUT + bn0 + c]);
        }
        __syncthreads();
        #pragma unroll 4
        for (int k = 0; k < 32; ++k) {
            float2 av[8]; float sv[4];
            #pragma unroll
            for (int m = 0; m < 8; ++m) av[m] = Asf[k][ty * 8 + m];
            #pragma unroll
            for (int n = 0; n < 4; ++n) sv[n] = Bsf[k][tx * 4 + n];
            #pragma unroll
            for (int m = 0; m < 8; ++m)
                #pragma unroll
                for (int n = 0; n < 4; ++n) {
                    ca[m][n] = fmaf(av[m].x, sv[n], ca[m][n]);
                    cb[m][n] = fmaf(av[m].y, sv[n], cb[m][n]);
                }
        }
        if (((s + 1) & 15) == 0) {
            #pragma unroll
            for (int m = 0; m < 8; ++m)
                #pragma unroll
                for (int n = 0; n < 4; ++n) {
                    ma[m][n] += ca[m][n]; ca[m][n] = 0.f;
                    mb[m][n] += cb[m][n]; cb[m][n] = 0.f;
                }
        }
        __syncthreads();
    }
    #pragma unroll
    for (int m = 0; m < 8; ++m) {
        int row = bm0 + ty * 8 + m;
        #pragma unroll
        for (int n = 0; n < 4; ++n) {
            int col = bn0 + tx * 4 + n;
            float r = ma[m][n] - mb[m][n];
            float conc = fabsf(r) / 409.6f;
            float hc = (r < 0.f) ? (1e-14f / conc) : conc;
            out[(size_t)row * NOUT + col] = (-logf(hc)) / 2.302585092994046f;
        }
    }
}

extern "C" void kernel_launch(void* const* d_in, const int* in_sizes, int n_in,
                              void* d_out, int out_size, void* d_ws, size_t ws_size,
                              hipStream_t stream) {
    const float* x = (const float*)d_in[0];
    const float* w = (const float*)d_in[1];
    float* out = (float*)d_out;

    const size_t nElem = (size_t)BATCH * NIN;
    // ws layout: AaT f32 | Ab u16 | signT u16 | signP u16  = 10 B/elem (168 MB)
    float*          aaT   = (float*)d_ws;
    unsigned short* ab    = (unsigned short*)((char*)d_ws + nElem * 4);
    unsigned short* signT = (unsigned short*)((char*)d_ws + nElem * 6);
    unsigned short* signP = (unsigned short*)((char*)d_ws + nElem * 8);

    if (ws_size >= nElem * 10) {
        precompute_all <<<dim3(64, 128), 256, 0, stream>>>(x, w, aaT, ab, signT, signP);
        acid_base_fused<<<dim3(32, 32), 256, 0, stream>>>(aaT, signP, ab, signT, out);
    } else {
        acid_gemm_fly<<<dim3(NOUT / 64, BATCH / 128), dim3(256), 0, stream>>>(x, w, out);
    }
}

// Round 22
// 2071.202 us; speedup vs baseline: 1.0068x; 1.0068x over previous
//
#include <hip/hip_runtime.h>
#include <math.h>

#define BATCH 4096
#define NIN   4096
#define NOUT  4096
// R9-verified ACID ORDER (frozen): [512x8] k-panels, single ascending fmaf
// chain, fold every 512 k, f32 epilogue. BASE on MFMA pipe (R13/R19-verified).
// R22: BARRIER-FREE main loop. Wave-private staging (wave w reads only As
// cols w*32..+31; B copy duplicated per wave) via per-lane-gather
// global_load_lds; sync = per-wave s_waitcnt only. 256 __syncthreads -> 1.

typedef __attribute__((ext_vector_type(8))) short bf16x8;
typedef __attribute__((ext_vector_type(8))) unsigned short u16x8;
typedef __attribute__((ext_vector_type(4))) float f32x4;

__device__ __forceinline__ float2 compute_terms(float xv) {
    float h  = (float)exp10(-(double)xv);
    float oh = 1e-14f / h;
    return make_float2(h * 0.1f, oh * 0.1f);
}
__device__ __forceinline__ unsigned short bf16_rne(float v) {
    unsigned int b = __float_as_uint(v);
    return (unsigned short)((b + 0x7FFFu + ((b >> 16) & 1u)) >> 16);
}
__device__ __forceinline__ float signf_of(float wv) {
    return (wv > 0.f) ? 1.f : ((wv < 0.f) ? -1.f : 0.f);
}
__device__ __forceinline__ unsigned short signbf16_of(float wv) {
    return (wv > 0.f) ? 0x3F80u : ((wv < 0.f) ? 0xBF80u : 0u);
}

#define GLOAD16(g, l)                                                        \
    __builtin_amdgcn_global_load_lds(                                        \
        (const __attribute__((address_space(1))) void*)(g),                  \
        (__attribute__((address_space(3))) void*)(l), 16, 0, 0)

// --- merged precompute (R21-verified) ---
__global__ __launch_bounds__(256) void precompute_all(const float* __restrict__ x,
                                                      const float* __restrict__ w,
                                                      float* __restrict__ aaT,
                                                      unsigned short* __restrict__ ab,
                                                      unsigned short* __restrict__ sT,
                                                      unsigned short* __restrict__ sP) {
    const int tid = threadIdx.x;
    if (blockIdx.y < 64) {
        __shared__ float tile[64][65];
        const int m0 = blockIdx.y * 64, k0 = blockIdx.x * 64;
        #pragma unroll
        for (int it = 0; it < 4; ++it) {
            int idx = tid + it * 256;
            int row = idx >> 4, q = idx & 15;
            float4 xv = *(const float4*)(x + (size_t)(m0 + row) * NIN + k0 + q * 4);
            float2 t0 = compute_terms(xv.x), t1 = compute_terms(xv.y),
                   t2 = compute_terms(xv.z), t3 = compute_terms(xv.w);
            *(ushort4*)(ab + (size_t)(m0 + row) * NIN + k0 + q * 4) =
                make_ushort4(bf16_rne(t0.y), bf16_rne(t1.y), bf16_rne(t2.y), bf16_rne(t3.y));
            tile[row][q * 4 + 0] = t0.x; tile[row][q * 4 + 1] = t1.x;
            tile[row][q * 4 + 2] = t2.x; tile[row][q * 4 + 3] = t3.x;
        }
        __syncthreads();
        #pragma unroll
        for (int it = 0; it < 4; ++it) {
            int idx = tid + it * 256;
            int krow = idx >> 4, q = idx & 15;
            float4 v = make_float4(tile[q * 4 + 0][krow], tile[q * 4 + 1][krow],
                                   tile[q * 4 + 2][krow], tile[q * 4 + 3][krow]);
            *(float4*)(aaT + (size_t)(k0 + krow) * NIN + m0 + q * 4) = v;
        }
    } else {
        __shared__ unsigned short tileu[64][68];
        const int k0 = (blockIdx.y - 64) * 64, n0 = blockIdx.x * 64;
        #pragma unroll
        for (int it = 0; it < 4; ++it) {
            int idx = tid + it * 256;
            int krow = idx >> 4, q = idx & 15;
            float4 wv = *(const float4*)(w + (size_t)(k0 + krow) * NOUT + n0 + q * 4);
            ushort4 sg = make_ushort4(signbf16_of(wv.x), signbf16_of(wv.y),
                                      signbf16_of(wv.z), signbf16_of(wv.w));
            *(ushort4*)&tileu[krow][q * 4] = sg;
            int c0  = n0 + q * 4;
            int grp = c0 >> 7, wi = c0 & 127;
            int pos = grp * 128 + ((wi & 63) >> 2) * 8 + ((wi >> 6) & 1) * 4;
            *(ushort4*)(sP + (size_t)(k0 + krow) * NOUT + pos) = sg;
        }
        __syncthreads();
        #pragma unroll
        for (int it = 0; it < 2; ++it) {
            int idx = tid + it * 256;
            int n = idx >> 3, kc = idx & 7;
            u16x8 v;
            #pragma unroll
            for (int j = 0; j < 8; ++j) v[j] = tileu[kc * 8 + j][n];
            *(u16x8*)(sT + (size_t)(n0 + n) * NIN + k0 + kc * 8) = v;
        }
    }
}

// --- fused kernel: barrier-free acid VALU loop + base MFMA tail ---
// LDS 49152 B: As slices [w][2][16][32] f32 @0 (16 KB), Bs slices
// [w][2][16][128] u16 @16384 (32 KB); BoutH[128][68] f32 aliases @0 in tail.
__global__ __launch_bounds__(256, 3) void acid_base_fused(const float* __restrict__ AaT,
                                                          const unsigned short* __restrict__ SignP,
                                                          const unsigned short* __restrict__ Ab,
                                                          const unsigned short* __restrict__ SignT,
                                                          float* __restrict__ out) {
    __shared__ __align__(16) char smem[49152];

    const int tid = threadIdx.x;
    const int tx  = tid & 15;      // cols tx*4..+3 and 64+tx*4..+3 (permuted sn)
    const int ty  = tid >> 4;      // rows ty*8..+7
    const int w   = tid >> 6;      // wave
    const int l   = tid & 63;
    const int g   = l >> 4;        // MFMA k-group
    const int r16 = l & 15;
    const int ty3 = ty & 3;        // == l>>4
    const int bm0 = blockIdx.y * 128;
    const int bn0 = blockIdx.x * 128;

    float*        asf = (float*)(smem + w * 4096);           // [2][16][32] f32
    unsigned int* bsu = (unsigned int*)(smem + 16384 + w * 8192); // [2][16][64] u32
    float (*BoutH)[68] = (float (*)[68])smem;                // tail alias

    float ma[8][8] = {}, ca[8][8] = {};

    // wave-private gather staging: A 2 glds (8 k-rows x 32 cols each),
    // B 4 glds (4 k-rows x 128 cols each). LDS dest = uniform base (+lane*16 HW).
    #define AISSUE(s, b)                                                            \
        {                                                                           \
            const int k0_ = (s) * 16;                                               \
            _Pragma("unroll")                                                       \
            for (int j = 0; j < 2; ++j)                                             \
                GLOAD16(AaT + (size_t)(k0_ + j * 8 + (l >> 3)) * NIN                \
                            + bm0 + w * 32 + (l & 7) * 4,                           \
                        (char*)asf + (b) * 2048 + j * 1024);                        \
            _Pragma("unroll")                                                       \
            for (int j = 0; j < 4; ++j)                                             \
                GLOAD16(SignP + (size_t)(k0_ + j * 4 + (l >> 4)) * NOUT             \
                              + bn0 + (l & 15) * 8,                                 \
                        (char*)bsu + (b) * 4096 + j * 1024);                        \
        }

    // 16 ascending k; fold every 32 stages (= 512 k, R9-frozen schedule)
    #define ACOMP(s, b)                                                             \
        {                                                                           \
            _Pragma("unroll 4")                                                     \
            for (int k = 0; k < 16; ++k) {                                          \
                const float4 pa = *(const float4*)(asf + (b) * 512 + k * 32 + ty3 * 8);\
                const float4 pb = *(const float4*)(asf + (b) * 512 + k * 32 + ty3 * 8 + 4);\
                const uint4  su = *(const uint4*)(bsu + (b) * 1024 + k * 64 + tx * 4);\
                const float av[8] = {pa.x, pa.y, pa.z, pa.w, pb.x, pb.y, pb.z, pb.w};\
                const float sn[8] = {                                               \
                    __uint_as_float(su.x << 16), __uint_as_float(su.x & 0xFFFF0000u),\
                    __uint_as_float(su.y << 16), __uint_as_float(su.y & 0xFFFF0000u),\
                    __uint_as_float(su.z << 16), __uint_as_float(su.z & 0xFFFF0000u),\
                    __uint_as_float(su.w << 16), __uint_as_float(su.w & 0xFFFF0000u)};\
                _Pragma("unroll")                                                   \
                for (int m = 0; m < 8; ++m)                                         \
                    _Pragma("unroll")                                               \
                    for (int n = 0; n < 8; ++n)                                     \
                        ca[m][n] = fmaf(av[m], sn[n], ca[m][n]);                    \
            }                                                                       \
            if ((((s) + 1) & 31) == 0) {                                            \
                _Pragma("unroll")                                                   \
                for (int m = 0; m < 8; ++m)                                         \
                    _Pragma("unroll")                                               \
                    for (int n = 0; n < 8; ++n) {                                   \
                        ma[m][n] += ca[m][n]; ca[m][n] = 0.f;                       \
                    }                                                               \
            }                                                                       \
        }

    #define WAVE_WAIT() asm volatile("s_waitcnt vmcnt(0) lgkmcnt(0)" ::: "memory")

    AISSUE(0, 0);
    WAVE_WAIT();

    for (int s = 0; s < 256; ++s) {
        const int b = s & 1;
        if (s + 1 < 256) AISSUE(s + 1, b ^ 1);   // prefetch under compute
        ACOMP(s, b);
        WAVE_WAIT();                              // own glds + ds_reads drained
    }

    // ---- base MFMA tail (R19/R20-verified): acc reuses ca's dead budget ----
    f32x4 acc[2][8] = {};
    {
        const unsigned short* a0 = Ab + (size_t)(bm0 + w * 32 + r16) * NIN + g * 8;
        const unsigned short* a1 = Ab + (size_t)(bm0 + w * 32 + 16 + r16) * NIN + g * 8;
        #pragma unroll 4
        for (int s = 0; s < 128; ++s) {
            const int k0 = s * 32;
            bf16x8 af0 = *(const bf16x8*)(a0 + k0);
            bf16x8 af1 = *(const bf16x8*)(a1 + k0);
            #pragma unroll
            for (int tc = 0; tc < 8; ++tc) {
                bf16x8 bf = *(const bf16x8*)(SignT + (size_t)(bn0 + tc * 16 + r16) * NIN + k0 + g * 8);
                acc[0][tc] = __builtin_amdgcn_mfma_f32_16x16x32_bf16(af0, bf, acc[0][tc], 0, 0, 0);
                acc[1][tc] = __builtin_amdgcn_mfma_f32_16x16x32_bf16(af1, bf, acc[1][tc], 0, 0, 0);
            }
        }
    }

    // ---- combine + epilogue, two column halves (R18/R20-verified) ----
    __syncthreads();   // all waves done with private bufs; BoutH alias safe
    #pragma unroll
    for (int hh = 0; hh < 2; ++hh) {
        #pragma unroll
        for (int tr = 0; tr < 2; ++tr)
            #pragma unroll
            for (int tc = 0; tc < 4; ++tc)
                #pragma unroll
                for (int rr = 0; rr < 4; ++rr)
                    BoutH[w * 32 + tr * 16 + g * 4 + rr][tc * 16 + r16] = acc[tr][hh * 4 + tc][rr];
        __syncthreads();
        #pragma unroll
        for (int m = 0; m < 8; ++m) {
            const int row = ty * 8 + m;
            const float4 bv = *(const float4*)&BoutH[row][tx * 4];
            const float bb[4] = {bv.x, bv.y, bv.z, bv.w};
            float ph[4];
            #pragma unroll
            for (int n = 0; n < 4; ++n) {
                float r    = ma[m][hh * 4 + n] - bb[n];
                float conc = fabsf(r) / 409.6f;
                float hc   = (r < 0.f) ? (1e-14f / conc) : conc;
                ph[n]      = (-logf(hc)) / 2.302585092994046f;
            }
            *(float4*)(out + (size_t)(bm0 + row) * NOUT + bn0 + hh * 64 + tx * 4) =
                make_float4(ph[0], ph[1], ph[2], ph[3]);
        }
        __syncthreads();
    }
    #undef AISSUE
    #undef ACOMP
    #undef WAVE_WAIT
}

// Fallback (ws too small): R9's proven all-VALU kernel, on-the-fly terms.
__global__ __launch_bounds__(256, 2) void acid_gemm_fly(const float* __restrict__ X,
                                                        const float* __restrict__ W,
                                                        float* __restrict__ out) {
    __shared__ float2 Asf[32][128 + 2];
    __shared__ float  Bsf[32][64];
    const int tid = threadIdx.x;
    const int tx = tid & 15, ty = tid >> 4;
    const int bm0 = blockIdx.y * 128, bn0 = blockIdx.x * 64;
    float ma[8][4] = {}, mb[8][4] = {}, ca[8][4] = {}, cb[8][4] = {};
    for (int s = 0; s < 128; ++s) {
        const int k0 = s * 32;
        for (int idx = tid; idx < 128 * 32; idx += 256) {
            int m = idx >> 5, k = idx & 31;
            Asf[k][m] = compute_terms(X[(size_t)(bm0 + m) * NIN + k0 + k]);
        }
        for (int idx = tid; idx < 32 * 64; idx += 256) {
            int k = idx >> 6, c = idx & 63;
            Bsf[k][c] = signf_of(W[(size_t)(k0 + k) * NOUT + bn0 + c]);
        }
        __syncthreads();
        #pragma unroll 4
        for (int k = 0; k < 32; ++k) {
            float2 av[8]; float sv[4];
            #pragma unroll
            for (int m = 0; m < 8; ++m) av[m] = Asf[k][ty * 8 + m];
            #pragma unroll
            for (int n = 0; n < 4; ++n) sv[n] = Bsf[k][tx * 4 + n];
            #pragma unroll
            for (int m = 0; m < 8; ++m)
                #pragma unroll
                for (int n = 0; n < 4; ++n) {
                    ca[m][n] = fmaf(av[m].x, sv[n], ca[m][n]);
                    cb[m][n] = fmaf(av[m].y, sv[n], cb[m][n]);
                }
        }
        if (((s + 1) & 15) == 0) {
            #pragma unroll
            for (int m = 0; m < 8; ++m)
                #pragma unroll
                for (int n = 0; n < 4; ++n) {
                    ma[m][n] += ca[m][n]; ca[m][n] = 0.f;
                    mb[m][n] += cb[m][n]; cb[m][n] = 0.f;
                }
        }
        __syncthreads();
    }
    #pragma unroll
    for (int m = 0; m < 8; ++m) {
        int row = bm0 + ty * 8 + m;
        #pragma unroll
        for (int n = 0; n < 4; ++n) {
            int col = bn0 + tx * 4 + n;
            float r = ma[m][n] - mb[m][n];
            float conc = fabsf(r) / 409.6f;
            float hc = (r < 0.f) ? (1e-14f / conc) : conc;
            out[(size_t)row * NOUT + col] = (-logf(hc)) / 2.302585092994046f;
        }
    }
}

extern "C" void kernel_launch(void* const* d_in, const int* in_sizes, int n_in,
                              void* d_out, int out_size, void* d_ws, size_t ws_size,
                              hipStream_t stream) {
    const float* x = (const float*)d_in[0];
    const float* w = (const float*)d_in[1];
    float* out = (float*)d_out;

    const size_t nElem = (size_t)BATCH * NIN;
    // ws layout: AaT f32 | Ab u16 | signT u16 | signP u16  = 10 B/elem (168 MB)
    float*          aaT   = (float*)d_ws;
    unsigned short* ab    = (unsigned short*)((char*)d_ws + nElem * 4);
    unsigned short* signT = (unsigned short*)((char*)d_ws + nElem * 6);
    unsigned short* signP = (unsigned short*)((char*)d_ws + nElem * 8);

    if (ws_size >= nElem * 10) {
        precompute_all <<<dim3(64, 128), 256, 0, stream>>>(x, w, aaT, ab, signT, signP);
        acid_base_fused<<<dim3(32, 32), 256, 0, stream>>>(aaT, signP, ab, signT, out);
    } else {
        acid_gemm_fly<<<dim3(NOUT / 64, BATCH / 128), dim3(256), 0, stream>>>(x, w, out);
    }
}

// Round 23
// 2002.068 us; speedup vs baseline: 1.0416x; 1.0345x over previous
//
#include <hip/hip_runtime.h>
#include <math.h>

#define BATCH 4096
#define NIN   4096
#define NOUT  4096
// R9-verified ACID ORDER (frozen): [512x8] k-panels, single ascending fmaf
// chain, fold every 512 k, f32 epilogue. BASE on MFMA pipe (R13/R19-verified).
// R23 = R20 (best: 2001 us) + T5 s_setprio around MFMA tail (diverse-phase
// regime: staggered blocks put tail-MFMA waves and loop-VALU waves on the
// same CU). R21 (bf16 signs) and R22 (barrier-free) measured null/regressive
// -> reverted. Ledger: acid loop is at the DS/VALU balance point.

typedef __attribute__((ext_vector_type(8))) short bf16x8;
typedef __attribute__((ext_vector_type(8))) unsigned short u16x8;
typedef __attribute__((ext_vector_type(4))) float f32x4;

__device__ __forceinline__ float2 compute_terms(float xv) {
    float h  = (float)exp10(-(double)xv);
    float oh = 1e-14f / h;
    return make_float2(h * 0.1f, oh * 0.1f);
}
__device__ __forceinline__ unsigned short bf16_rne(float v) {
    unsigned int b = __float_as_uint(v);
    return (unsigned short)((b + 0x7FFFu + ((b >> 16) & 1u)) >> 16);
}
__device__ __forceinline__ float signf_of(float wv) {
    return (wv > 0.f) ? 1.f : ((wv < 0.f) ? -1.f : 0.f);
}
__device__ __forceinline__ unsigned short signbf16_of(float wv) {
    return (wv > 0.f) ? 0x3F80u : ((wv < 0.f) ? 0xBF80u : 0u);
}

#define GLOAD16(g, l)                                                        \
    __builtin_amdgcn_global_load_lds(                                        \
        (const __attribute__((address_space(1))) void*)(g),                  \
        (__attribute__((address_space(3))) void*)(l), 16, 0, 0)

// --- merged precompute: blocks y<64 process x -> AaT[k][m] f32 + Ab[m][k] bf16;
//     blocks y>=64 process w -> signT[n][k] bf16 + signF[k][n] f32 ---
__global__ __launch_bounds__(256) void precompute_all(const float* __restrict__ x,
                                                      const float* __restrict__ w,
                                                      float* __restrict__ aaT,
                                                      unsigned short* __restrict__ ab,
                                                      unsigned short* __restrict__ sT,
                                                      float* __restrict__ sF) {
    const int tid = threadIdx.x;
    if (blockIdx.y < 64) {
        __shared__ float tile[64][65];
        const int m0 = blockIdx.y * 64, k0 = blockIdx.x * 64;
        #pragma unroll
        for (int it = 0; it < 4; ++it) {
            int idx = tid + it * 256;
            int row = idx >> 4, q = idx & 15;
            float4 xv = *(const float4*)(x + (size_t)(m0 + row) * NIN + k0 + q * 4);
            float2 t0 = compute_terms(xv.x), t1 = compute_terms(xv.y),
                   t2 = compute_terms(xv.z), t3 = compute_terms(xv.w);
            *(ushort4*)(ab + (size_t)(m0 + row) * NIN + k0 + q * 4) =
                make_ushort4(bf16_rne(t0.y), bf16_rne(t1.y), bf16_rne(t2.y), bf16_rne(t3.y));
            tile[row][q * 4 + 0] = t0.x; tile[row][q * 4 + 1] = t1.x;
            tile[row][q * 4 + 2] = t2.x; tile[row][q * 4 + 3] = t3.x;
        }
        __syncthreads();
        #pragma unroll
        for (int it = 0; it < 4; ++it) {
            int idx = tid + it * 256;
            int krow = idx >> 4, q = idx & 15;
            float4 v = make_float4(tile[q * 4 + 0][krow], tile[q * 4 + 1][krow],
                                   tile[q * 4 + 2][krow], tile[q * 4 + 3][krow]);
            *(float4*)(aaT + (size_t)(k0 + krow) * NIN + m0 + q * 4) = v;
        }
    } else {
        __shared__ unsigned short tileu[64][68];
        const int k0 = (blockIdx.y - 64) * 64, n0 = blockIdx.x * 64;
        #pragma unroll
        for (int it = 0; it < 4; ++it) {
            int idx = tid + it * 256;
            int krow = idx >> 4, q = idx & 15;
            float4 wv = *(const float4*)(w + (size_t)(k0 + krow) * NOUT + n0 + q * 4);
            *(ushort4*)&tileu[krow][q * 4] =
                make_ushort4(signbf16_of(wv.x), signbf16_of(wv.y), signbf16_of(wv.z), signbf16_of(wv.w));
            *(float4*)(sF + (size_t)(k0 + krow) * NOUT + n0 + q * 4) =
                make_float4(signf_of(wv.x), signf_of(wv.y), signf_of(wv.z), signf_of(wv.w));
        }
        __syncthreads();
        #pragma unroll
        for (int it = 0; it < 2; ++it) {
            int idx = tid + it * 256;
            int n = idx >> 3, kc = idx & 7;
            u16x8 v;
            #pragma unroll
            for (int j = 0; j < 8; ++j) v[j] = tileu[kc * 8 + j][n];
            *(u16x8*)(sT + (size_t)(n0 + n) * NIN + k0 + kc * 8) = v;
        }
    }
}

// --- fused kernel: acid VALU main loop (R19-verified) + base MFMA tail ---
// LDS: As[2][16][128] + Bs[2][16][128] f32 = 32768 B, aliased by
// BoutH[128][68] f32 = 34816 B in the tail -> block LDS = 34816.
// Regs: main loop ca+ma (ma->AGPR, R19: VGPR 84); tail acc reuses ca's
// budget (ca dead after last fold) -> peak ~150 <= 170 for 3 waves/SIMD.
__global__ __launch_bounds__(256, 3) void acid_base_fused(const float* __restrict__ AaT,
                                                          const float* __restrict__ SignF,
                                                          const unsigned short* __restrict__ Ab,
                                                          const unsigned short* __restrict__ SignT,
                                                          float* __restrict__ out) {
    __shared__ __align__(16) char smem[34816];
    float (*As)[16][128] = (float (*)[16][128])smem;            // [2][16][128]
    float (*Bs)[16][128] = (float (*)[16][128])(smem + 16384);  // [2][16][128]
    float (*BoutH)[68]   = (float (*)[68])smem;                 // [128][68] tail alias

    const int tid = threadIdx.x;
    const int tx  = tid & 15;      // cols tx*4..+3 and 64+tx*4..+3
    const int ty  = tid >> 4;      // rows ty*8..+7
    const int w   = tid >> 6;      // wave
    const int l   = tid & 63;
    const int g   = l >> 4;        // MFMA k-group
    const int r16 = l & 15;
    const int bm0 = blockIdx.y * 128;
    const int bn0 = blockIdx.x * 128;

    const int lrow = (l >> 5);       // sub-row within a 1024B glds
    const int lcol = (l & 31) * 4;   // f32 col within 128-wide row

    float ma[8][8] = {}, ca[8][8] = {};

    #define AISSUE(s, b)                                                            \
        {                                                                           \
            const int k0_ = (s) * 16;                                               \
            _Pragma("unroll")                                                       \
            for (int j = 0; j < 2; ++j) {                                           \
                const int kr_ = w * 4 + 2 * j;                                      \
                GLOAD16(AaT   + (size_t)(k0_ + kr_ + lrow) * NIN + bm0 + lcol,      \
                        &As[b][kr_][0]);                                            \
                GLOAD16(SignF + (size_t)(k0_ + kr_ + lrow) * NIN + bn0 + lcol,      \
                        &Bs[b][kr_][0]);                                            \
            }                                                                       \
        }

    #define ACOMP(s, b)                                                             \
        {                                                                           \
            _Pragma("unroll 4")                                                     \
            for (int k = 0; k < 16; ++k) {                                          \
                const float4 pa = *(const float4*)&As[b][k][ty * 8];                \
                const float4 pb = *(const float4*)&As[b][k][ty * 8 + 4];            \
                const float4 s0 = *(const float4*)&Bs[b][k][tx * 4];                \
                const float4 s1 = *(const float4*)&Bs[b][k][64 + tx * 4];           \
                const float av[8] = {pa.x, pa.y, pa.z, pa.w, pb.x, pb.y, pb.z, pb.w};\
                const float sn[8] = {s0.x, s0.y, s0.z, s0.w, s1.x, s1.y, s1.z, s1.w};\
                _Pragma("unroll")                                                   \
                for (int m = 0; m < 8; ++m)                                         \
                    _Pragma("unroll")                                               \
                    for (int n = 0; n < 8; ++n)                                     \
                        ca[m][n] = fmaf(av[m], sn[n], ca[m][n]);                    \
            }                                                                       \
            if ((((s) + 1) & 31) == 0) {                                            \
                _Pragma("unroll")                                                   \
                for (int m = 0; m < 8; ++m)                                         \
                    _Pragma("unroll")                                               \
                    for (int n = 0; n < 8; ++n) {                                   \
                        ma[m][n] += ca[m][n]; ca[m][n] = 0.f;                       \
                    }                                                               \
            }                                                                       \
        }

    AISSUE(0, 0);
    __syncthreads();   // buf0 ready

    for (int s2 = 0; s2 < 128; ++s2) {
        const int s = 2 * s2;
        AISSUE(s + 1, 1);
        ACOMP(s, 0);
        __syncthreads();
        if (s + 2 < 256) AISSUE(s + 2, 0);
        ACOMP(s + 1, 1);
        __syncthreads();
    }

    // ---- base MFMA tail (R19/R20-verified): acc reuses ca's dead budget ----
    // T5: raise wave priority through the MFMA cluster — CU hosts staggered
    // blocks (some still in VALU loop), so the scheduler has roles to arbitrate.
    f32x4 acc[2][8] = {};
    __builtin_amdgcn_s_setprio(1);
    {
        const unsigned short* a0 = Ab + (size_t)(bm0 + w * 32 + r16) * NIN + g * 8;
        const unsigned short* a1 = Ab + (size_t)(bm0 + w * 32 + 16 + r16) * NIN + g * 8;
        #pragma unroll 4
        for (int s = 0; s < 128; ++s) {
            const int k0 = s * 32;
            bf16x8 af0 = *(const bf16x8*)(a0 + k0);
            bf16x8 af1 = *(const bf16x8*)(a1 + k0);
            #pragma unroll
            for (int tc = 0; tc < 8; ++tc) {
                bf16x8 bf = *(const bf16x8*)(SignT + (size_t)(bn0 + tc * 16 + r16) * NIN + k0 + g * 8);
                acc[0][tc] = __builtin_amdgcn_mfma_f32_16x16x32_bf16(af0, bf, acc[0][tc], 0, 0, 0);
                acc[1][tc] = __builtin_amdgcn_mfma_f32_16x16x32_bf16(af1, bf, acc[1][tc], 0, 0, 0);
            }
        }
    }
    __builtin_amdgcn_s_setprio(0);

    // ---- combine + epilogue, two column halves (R18/R19-verified) ----
    __syncthreads();   // As/Bs dead; BoutH alias safe
    #pragma unroll
    for (int hh = 0; hh < 2; ++hh) {
        #pragma unroll
        for (int tr = 0; tr < 2; ++tr)
            #pragma unroll
            for (int tc = 0; tc < 4; ++tc)
                #pragma unroll
                for (int rr = 0; rr < 4; ++rr)
                    BoutH[w * 32 + tr * 16 + g * 4 + rr][tc * 16 + r16] = acc[tr][hh * 4 + tc][rr];
        __syncthreads();
        #pragma unroll
        for (int m = 0; m < 8; ++m) {
            const int row = ty * 8 + m;
            const float4 bv = *(const float4*)&BoutH[row][tx * 4];
            const float bb[4] = {bv.x, bv.y, bv.z, bv.w};
            float ph[4];
            #pragma unroll
            for (int n = 0; n < 4; ++n) {
                float r    = ma[m][hh * 4 + n] - bb[n];
                float conc = fabsf(r) / 409.6f;
                float hc   = (r < 0.f) ? (1e-14f / conc) : conc;
                ph[n]      = (-logf(hc)) / 2.302585092994046f;
            }
            *(float4*)(out + (size_t)(bm0 + row) * NOUT + bn0 + hh * 64 + tx * 4) =
                make_float4(ph[0], ph[1], ph[2], ph[3]);
        }
        __syncthreads();
    }
    #undef AISSUE
    #undef ACOMP
}

// Fallback (ws too small): R9's proven all-VALU kernel, on-the-fly terms.
__global__ __launch_bounds__(256, 2) void acid_gemm_fly(const float* __restrict__ X,
                                                        const float* __restrict__ W,
                                                        float* __restrict__ out) {
    __shared__ float2 Asf[32][128 + 2];
    __shared__ float  Bsf[32][64];
    const int tid = threadIdx.x;
    const int tx = tid & 15, ty = tid >> 4;
    const int bm0 = blockIdx.y * 128, bn0 = blockIdx.x * 64;
    float ma[8][4] = {}, mb[8][4] = {}, ca[8][4] = {}, cb[8][4] = {};
    for (int s = 0; s < 128; ++s) {
        const int k0 = s * 32;
        for (int idx = tid; idx < 128 * 32; idx += 256) {
            int m = idx >> 5, k = idx & 31;
            Asf[k][m] = compute_terms(X[(size_t)(bm0 + m) * NIN + k0 + k]);
        }
        for (int idx = tid; idx < 32 * 64; idx += 256) {
            int k = idx >> 6, c = idx & 63;
            Bsf[k][c] = signf_of(W[(size_t)(k0 + k) * NOUT + bn0 + c]);
        }
        __syncthreads();
        #pragma unroll 4
        for (int k = 0; k < 32; ++k) {
            float2 av[8]; float sv[4];
            #pragma unroll
            for (int m = 0; m < 8; ++m) av[m] = Asf[k][ty * 8 + m];
            #pragma unroll
            for (int n = 0; n < 4; ++n) sv[n] = Bsf[k][tx * 4 + n];
            #pragma unroll
            for (int m = 0; m < 8; ++m)
                #pragma unroll
                for (int n = 0; n < 4; ++n) {
                    ca[m][n] = fmaf(av[m].x, sv[n], ca[m][n]);
                    cb[m][n] = fmaf(av[m].y, sv[n], cb[m][n]);
                }
        }
        if (((s + 1) & 15) == 0) {
            #pragma unroll
            for (int m = 0; m < 8; ++m)
                #pragma unroll
                for (int n = 0; n < 4; ++n) {
                    ma[m][n] += ca[m][n]; ca[m][n] = 0.f;
                    mb[m][n] += cb[m][n]; cb[m][n] = 0.f;
                }
        }
        __syncthreads();
    }
    #pragma unroll
    for (int m = 0; m < 8; ++m) {
        int row = bm0 + ty * 8 + m;
        #pragma unroll
        for (int n = 0; n < 4; ++n) {
            int col = bn0 + tx * 4 + n;
            float r = ma[m][n] - mb[m][n];
            float conc = fabsf(r) / 409.6f;
            float hc = (r < 0.f) ? (1e-14f / conc) : conc;
            out[(size_t)row * NOUT + col] = (-logf(hc)) / 2.302585092994046f;
        }
    }
}

extern "C" void kernel_launch(void* const* d_in, const int* in_sizes, int n_in,
                              void* d_out, int out_size, void* d_ws, size_t ws_size,
                              hipStream_t stream) {
    const float* x = (const float*)d_in[0];
    const float* w = (const float*)d_in[1];
    float* out = (float*)d_out;

    const size_t nElem = (size_t)BATCH * NIN;
    // ws layout: AaT f32 | Ab u16 | signT u16 | signF f32  = 12 B/elem (201 MB)
    float*          aaT   = (float*)d_ws;
    unsigned short* ab    = (unsigned short*)((char*)d_ws + nElem * 4);
    unsigned short* signT = (unsigned short*)((char*)d_ws + nElem * 6);
    float*          signF = (float*)((char*)d_ws + nElem * 8);

    if (ws_size >= nElem * 12) {
        precompute_all <<<dim3(64, 128), 256, 0, stream>>>(x, w, aaT, ab, signT, signF);
        acid_base_fused<<<dim3(32, 32), 256, 0, stream>>>(aaT, signF, ab, signT, out);
    } else {
        acid_gemm_fly<<<dim3(NOUT / 64, BATCH / 128), dim3(256), 0, stream>>>(x, w, out);
    }
}